// Round 13
// baseline (255.097 us; speedup 1.0000x reference)
//
#include <hip/hip_runtime.h>
#include <hip/hip_fp16.h>

// Guided filter, B=4 H=1024 W=1024 C=4 f32 NHWC, r from d_in[2] (expected <=40).
// R12->R13: concurrency fix. All ~185us configs ran 1 block/CU (grid==256 or
// LDS-blocked); the 2.35 TB/s effective-BW ceiling is a per-CU outstanding-
// request limit. Now: half-width tiles (TILE=512 + HALO 40 -> scan 592,
// 1.16x read redundancy), BH=16, 2 tiles x 64 bands x B = 512 blocks =
// 2 INDEPENDENT blocks/CU (8 waves). Planes single-buffered (55KB -> two
// blocks fit); the scan's internal barrier already orders plane writes after
// all consume reads, so 2 lgkm-only barriers/row suffice.
// kfusedAB: I,p -> vert sliding sums {I,p,Ip,II} (regs) -> per-row block scan
//           -> horizontal box -> A,b out (fp16).
// kfusedQ : same over {A,b}; q = meanA*I + meanb -> d_out (f32).
// N = cntH(h)*cntW(w) analytic.

#define HD 1024
#define WD 1024
#define ROW4 WD
#define IMG4 ((size_t)HD * ROW4)
#define IMGF (IMG4 * 4)
#define BH 16                        // output rows per block
#define NB (HD / BH)                 // 64 bands
#define TILE 512                     // output pixels per block
#define NTILE (WD / TILE)            // 2
#define HALO 40
#define SCANW (TILE + 2 * HALO)      // 592
#define TPB 256
#define PPT 3                        // scan px/thread: 768 >= 592
#define OPT 2                        // output px/thread: 512/256
#define PFXN 865                     // idx4(768)+1
#define EPS 1e-8f

__device__ __forceinline__ int idx4(int p) { return p + (p >> 3); }

// lgkm-only barrier: global loads stay in flight across it.
__device__ __forceinline__ void barrier_lds() {
    asm volatile("s_waitcnt lgkmcnt(0)" ::: "memory");
    __builtin_amdgcn_s_barrier();
}

struct H4 { __half2 lo, hi; };

__device__ __forceinline__ H4 pack4(float4 v) {
    H4 h; h.lo = __floats2half2_rn(v.x, v.y); h.hi = __floats2half2_rn(v.z, v.w);
    return h;
}
__device__ __forceinline__ float4 unpack4(H4 h) {
    float2 l = __half22float2(h.lo), u = __half22float2(h.hi);
    return make_float4(l.x, l.y, u.x, u.y);
}
__device__ __forceinline__ float4 packAB(H4 a, H4 b) {
    union { H4 h[2]; float4 f; } u; u.h[0] = a; u.h[1] = b; return u.f;
}
__device__ __forceinline__ float4 f4add(float4 a, float4 b) {
    return make_float4(a.x + b.x, a.y + b.y, a.z + b.z, a.w + b.w);
}
__device__ __forceinline__ float4 f4sub(float4 a, float4 b) {
    return make_float4(a.x - b.x, a.y - b.y, a.z - b.z, a.w - b.w);
}
__device__ __forceinline__ float4 f4s(float4 a, float s) {
    return make_float4(a.x * s, a.y * s, a.z * s, a.w * s);
}
__device__ __forceinline__ float4 f4mul(float4 a, float4 b) {
    return make_float4(a.x * b.x, a.y * b.y, a.z * b.z, a.w * b.w);
}
__device__ __forceinline__ float4 shup4(float4 v, int d) {
    return make_float4(__shfl_up(v.x, d), __shfl_up(v.y, d), __shfl_up(v.z, d), __shfl_up(v.w, d));
}
// bx in [0,128): xcd = bx&7 gets bands 8xcd..8xcd+7, both tiles of a band on
// the same XCD (adjacent bands share warm-up rows -> L2 locality). Bijective.
__device__ __forceinline__ void decode_bx(int bx, int& tile, int& band) {
    int xcd = bx & 7, inner = bx >> 3;      // inner in [0,16)
    tile = inner & 1;
    band = (xcd << 3) | (inner >> 1);
}

// Block scan of 4 fields (PPT=3/thread) into swizzled planes pl[f][idx4(p)].
// 2 lgkm barriers. Single-buffered is safe: plane writes happen only after
// the internal barrier that all consume-phase waves have passed.
__device__ __forceinline__ void scan4d(
    float4 (*pl)[PFXN], float4 (*wt)[4],
    const float4* s0, const float4* s1, const float4* s2, const float4* s3,
    int t, int lane, int wv)
{
    const float4 z4 = make_float4(0.f, 0.f, 0.f, 0.f);
    float4 p0[PPT], p1[PPT], p2[PPT], p3[PPT];
    p0[0] = s0[0]; p1[0] = s1[0]; p2[0] = s2[0]; p3[0] = s3[0];
    #pragma unroll
    for (int i = 1; i < PPT; ++i) {
        p0[i] = f4add(p0[i-1], s0[i]); p1[i] = f4add(p1[i-1], s1[i]);
        p2[i] = f4add(p2[i-1], s2[i]); p3[i] = f4add(p3[i-1], s3[i]);
    }
    float4 i0 = p0[PPT-1], i1 = p1[PPT-1], i2 = p2[PPT-1], i3 = p3[PPT-1];
    #pragma unroll
    for (int d = 1; d < 64; d <<= 1) {
        float4 t0 = shup4(i0, d), t1 = shup4(i1, d), t2 = shup4(i2, d), t3 = shup4(i3, d);
        if (lane >= d) {
            i0 = f4add(i0, t0); i1 = f4add(i1, t1);
            i2 = f4add(i2, t2); i3 = f4add(i3, t3);
        }
    }
    float4 e0 = shup4(i0, 1), e1 = shup4(i1, 1), e2 = shup4(i2, 1), e3 = shup4(i3, 1);
    if (lane == 0) { e0 = z4; e1 = z4; e2 = z4; e3 = z4; }
    if (lane == 63) { wt[wv][0] = i0; wt[wv][1] = i1; wt[wv][2] = i2; wt[wv][3] = i3; }
    barrier_lds();
    for (int wq = 0; wq < wv; ++wq) {
        e0 = f4add(e0, wt[wq][0]); e1 = f4add(e1, wt[wq][1]);
        e2 = f4add(e2, wt[wq][2]); e3 = f4add(e3, wt[wq][3]);
    }
    if (t == 0) {
        pl[0][idx4(0)] = z4; pl[1][idx4(0)] = z4;
        pl[2][idx4(0)] = z4; pl[3][idx4(0)] = z4;
    }
    #pragma unroll
    for (int i = 0; i < PPT; ++i) {
        int p = PPT * t + 1 + i;
        pl[0][idx4(p)] = f4add(e0, p0[i]);
        pl[1][idx4(p)] = f4add(e1, p1[i]);
        pl[2][idx4(p)] = f4add(e2, p2[i]);
        pl[3][idx4(p)] = f4add(e3, p3[i]);
    }
    barrier_lds();
}

__device__ __forceinline__ void scan2d(
    float4 (*pl)[PFXN], float4 (*wt)[2],
    const float4* s0, const float4* s1, int t, int lane, int wv)
{
    const float4 z4 = make_float4(0.f, 0.f, 0.f, 0.f);
    float4 p0[PPT], p1[PPT];
    p0[0] = s0[0]; p1[0] = s1[0];
    #pragma unroll
    for (int i = 1; i < PPT; ++i) {
        p0[i] = f4add(p0[i-1], s0[i]); p1[i] = f4add(p1[i-1], s1[i]);
    }
    float4 i0 = p0[PPT-1], i1 = p1[PPT-1];
    #pragma unroll
    for (int d = 1; d < 64; d <<= 1) {
        float4 t0 = shup4(i0, d), t1 = shup4(i1, d);
        if (lane >= d) { i0 = f4add(i0, t0); i1 = f4add(i1, t1); }
    }
    float4 e0 = shup4(i0, 1), e1 = shup4(i1, 1);
    if (lane == 0) { e0 = z4; e1 = z4; }
    if (lane == 63) { wt[wv][0] = i0; wt[wv][1] = i1; }
    barrier_lds();
    for (int wq = 0; wq < wv; ++wq) {
        e0 = f4add(e0, wt[wq][0]); e1 = f4add(e1, wt[wq][1]);
    }
    if (t == 0) { pl[0][idx4(0)] = z4; pl[1][idx4(0)] = z4; }
    #pragma unroll
    for (int i = 0; i < PPT; ++i) {
        int p = PPT * t + 1 + i;
        pl[0][idx4(p)] = f4add(e0, p0[i]);
        pl[1][idx4(p)] = f4add(e1, p1[i]);
    }
    barrier_lds();
}

// ---------------- KA: I,p -> A,b (fp16) ----------------
__global__ __launch_bounds__(TPB, 2) void kfusedAB(
    const float4* __restrict__ I4, const float4* __restrict__ P4,
    H4* __restrict__ Aout, H4* __restrict__ Bout,
    const int* __restrict__ rptr)
{
    __shared__ float4 pl[4][PFXN];      // 55.4 KB -> 2 blocks/CU
    __shared__ float4 wt[4][4];
    const int r = *rptr;
    const int t = threadIdx.x, lane = t & 63, wv = t >> 6;
    int tile, band; decode_bx(blockIdx.x, tile, band);
    const int h0 = band * BH;
    const int T = tile * TILE;
    const int seg0 = T - HALO;
    const size_t imgb = (size_t)blockIdx.y * IMG4;
    const float4* Iimg = I4 + imgb;
    const float4* Pimg = P4 + imgb;
    H4* Ao = Aout + imgb;
    H4* Bo = Bout + imgb;
    const float4 z4 = make_float4(0.f, 0.f, 0.f, 0.f);

    // scan columns
    int cc[PPT]; float cw[PPT];
    #pragma unroll
    for (int i = 0; i < PPT; ++i) {
        int p = PPT * t + i;
        int c = seg0 + p;
        bool ok = (p < SCANW) && (c >= 0) && (c < WD);
        cw[i] = ok ? 1.f : 0.f;
        cc[i] = ok ? c : 0;
    }

    float4 sI[PPT], sp[PPT], sIp[PPT], sII[PPT];
    #pragma unroll
    for (int i = 0; i < PPT; ++i) { sI[i] = z4; sp[i] = z4; sIp[i] = z4; sII[i] = z4; }

    int lo = h0 - r; if (lo < 0) lo = 0;
    int hi = h0 + r; if (hi > HD - 1) hi = HD - 1;
    int j = lo;
    for (; j + 3 <= hi; j += 4) {
        float4 a[4][PPT], c[4][PPT];
        #pragma unroll
        for (int k = 0; k < 4; ++k) {
            const float4* Ir = Iimg + (size_t)(j + k) * ROW4;
            const float4* Pr = Pimg + (size_t)(j + k) * ROW4;
            #pragma unroll
            for (int i = 0; i < PPT; ++i) {
                a[k][i] = f4s(Ir[cc[i]], cw[i]);
                c[k][i] = f4s(Pr[cc[i]], cw[i]);
            }
        }
        #pragma unroll
        for (int k = 0; k < 4; ++k)
            #pragma unroll
            for (int i = 0; i < PPT; ++i) {
                sI[i] = f4add(sI[i], a[k][i]);
                sp[i] = f4add(sp[i], c[k][i]);
                sIp[i] = f4add(sIp[i], f4mul(a[k][i], c[k][i]));
                sII[i] = f4add(sII[i], f4mul(a[k][i], a[k][i]));
            }
    }
    for (; j <= hi; ++j) {
        const float4* Ir = Iimg + (size_t)j * ROW4;
        const float4* Pr = Pimg + (size_t)j * ROW4;
        #pragma unroll
        for (int i = 0; i < PPT; ++i) {
            float4 a = f4s(Ir[cc[i]], cw[i]), c = f4s(Pr[cc[i]], cw[i]);
            sI[i] = f4add(sI[i], a); sp[i] = f4add(sp[i], c);
            sIp[i] = f4add(sIp[i], f4mul(a, c));
            sII[i] = f4add(sII[i], f4mul(a, a));
        }
    }

    for (int h = h0; h < h0 + BH; ++h) {
        // early-issue slide loads; lgkm barriers let them ride through
        int ja = h + 1 + r, js = h - r;
        float wa  = (ja <= HD - 1) ? 1.f : 0.f;
        float wsb = (js >= 0) ? 1.f : 0.f;
        int jac = (ja <= HD - 1) ? ja : HD - 1;
        int jsc = (js >= 0) ? js : 0;
        const float4* Iar = Iimg + (size_t)jac * ROW4;
        const float4* Par = Pimg + (size_t)jac * ROW4;
        const float4* Isr = Iimg + (size_t)jsc * ROW4;
        const float4* Psr = Pimg + (size_t)jsc * ROW4;
        float4 La[PPT], Ca[PPT], Ls[PPT], Cs[PPT];
        #pragma unroll
        for (int i = 0; i < PPT; ++i) {
            La[i] = Iar[cc[i]]; Ca[i] = Par[cc[i]];
            Ls[i] = Isr[cc[i]]; Cs[i] = Psr[cc[i]];
        }

        int hl = h - r; if (hl < 0) hl = 0;
        int hh = h + r; if (hh > HD - 1) hh = HD - 1;
        const float cntH = (float)(hh - hl + 1);

        scan4d(pl, wt, sI, sp, sIp, sII, t, lane, wv);

        H4 av[OPT], bv[OPT];
        #pragma unroll
        for (int i = 0; i < OPT; ++i) {
            int wp = T + OPT * t + i;           // global output pixel
            int wl = wp - r; if (wl < 0) wl = 0;
            int wh2 = wp + r; if (wh2 > WD - 1) wh2 = WD - 1;
            float invN = 1.f / ((float)(wh2 - wl + 1) * cntH);
            int iA = idx4(wh2 + 1 - seg0), iB = idx4(wl - seg0);
            float4 mI  = f4s(f4sub(pl[0][iA], pl[0][iB]), invN);
            float4 mp  = f4s(f4sub(pl[1][iA], pl[1][iB]), invN);
            float4 mIp = f4s(f4sub(pl[2][iA], pl[2][iB]), invN);
            float4 mII = f4s(f4sub(pl[3][iA], pl[3][iB]), invN);
            float4 cov = f4sub(mIp, f4mul(mI, mp));
            float4 var = f4sub(mII, f4mul(mI, mI));
            float4 Av = make_float4(cov.x / (var.x + EPS), cov.y / (var.y + EPS),
                                    cov.z / (var.z + EPS), cov.w / (var.w + EPS));
            float4 Bv = f4sub(mp, f4mul(Av, mI));
            av[i] = pack4(Av); bv[i] = pack4(Bv);
        }
        *(float4*)(Ao + (size_t)h * ROW4 + T + OPT * t) = packAB(av[0], av[1]);
        *(float4*)(Bo + (size_t)h * ROW4 + T + OPT * t) = packAB(bv[0], bv[1]);
        // no trailing barrier needed (see scan4d comment)

        #pragma unroll
        for (int i = 0; i < PPT; ++i) {
            float4 A1 = f4s(La[i], wa * cw[i]),  C1 = f4s(Ca[i], wa * cw[i]);
            float4 A2 = f4s(Ls[i], wsb * cw[i]), C2 = f4s(Cs[i], wsb * cw[i]);
            sI[i] = f4add(f4sub(sI[i], A2), A1);
            sp[i] = f4add(f4sub(sp[i], C2), C1);
            sIp[i] = f4add(sIp[i], f4sub(f4mul(A1, C1), f4mul(A2, C2)));
            sII[i] = f4add(sII[i], f4sub(f4mul(A1, A1), f4mul(A2, A2)));
        }
    }
}

// ---------------- KB: A,b -> q = meanA*I + meanb ----------------
__global__ __launch_bounds__(TPB, 2) void kfusedQ(
    const H4* __restrict__ Ain, const H4* __restrict__ Bin,
    const float4* __restrict__ I4, float4* __restrict__ Qout,
    const int* __restrict__ rptr)
{
    __shared__ float4 pl[2][PFXN];      // 27.7 KB
    __shared__ float4 wt[4][2];
    const int r = *rptr;
    const int t = threadIdx.x, lane = t & 63, wv = t >> 6;
    int tile, band; decode_bx(blockIdx.x, tile, band);
    const int h0 = band * BH;
    const int T = tile * TILE;
    const int seg0 = T - HALO;
    const size_t imgb = (size_t)blockIdx.y * IMG4;
    const H4* Aimg = Ain + imgb;
    const H4* Bimg = Bin + imgb;
    const float4* Iimg = I4 + imgb;
    const float4 z4 = make_float4(0.f, 0.f, 0.f, 0.f);

    int cc[PPT]; float cw[PPT];
    #pragma unroll
    for (int i = 0; i < PPT; ++i) {
        int p = PPT * t + i;
        int c = seg0 + p;
        bool ok = (p < SCANW) && (c >= 0) && (c < WD);
        cw[i] = ok ? 1.f : 0.f;
        cc[i] = ok ? c : 0;
    }

    float4 sA[PPT], sB[PPT];
    #pragma unroll
    for (int i = 0; i < PPT; ++i) { sA[i] = z4; sB[i] = z4; }

    int lo = h0 - r; if (lo < 0) lo = 0;
    int hi = h0 + r; if (hi > HD - 1) hi = HD - 1;
    int j = lo;
    for (; j + 3 <= hi; j += 4) {
        H4 a[4][PPT], b[4][PPT];
        #pragma unroll
        for (int k = 0; k < 4; ++k) {
            const H4* Ar = Aimg + (size_t)(j + k) * ROW4;
            const H4* Br = Bimg + (size_t)(j + k) * ROW4;
            #pragma unroll
            for (int i = 0; i < PPT; ++i) { a[k][i] = Ar[cc[i]]; b[k][i] = Br[cc[i]]; }
        }
        #pragma unroll
        for (int k = 0; k < 4; ++k)
            #pragma unroll
            for (int i = 0; i < PPT; ++i) {
                sA[i] = f4add(sA[i], f4s(unpack4(a[k][i]), cw[i]));
                sB[i] = f4add(sB[i], f4s(unpack4(b[k][i]), cw[i]));
            }
    }
    for (; j <= hi; ++j) {
        const H4* Ar = Aimg + (size_t)j * ROW4;
        const H4* Br = Bimg + (size_t)j * ROW4;
        #pragma unroll
        for (int i = 0; i < PPT; ++i) {
            sA[i] = f4add(sA[i], f4s(unpack4(Ar[cc[i]]), cw[i]));
            sB[i] = f4add(sB[i], f4s(unpack4(Br[cc[i]]), cw[i]));
        }
    }

    for (int h = h0; h < h0 + BH; ++h) {
        int ja = h + 1 + r, js = h - r;
        float wa  = (ja <= HD - 1) ? 1.f : 0.f;
        float wsb = (js >= 0) ? 1.f : 0.f;
        int jac = (ja <= HD - 1) ? ja : HD - 1;
        int jsc = (js >= 0) ? js : 0;
        const H4* Aar = Aimg + (size_t)jac * ROW4;
        const H4* Bar = Bimg + (size_t)jac * ROW4;
        const H4* Asr = Aimg + (size_t)jsc * ROW4;
        const H4* Bsr = Bimg + (size_t)jsc * ROW4;
        H4 La[PPT], Lb[PPT], Sa[PPT], Sb[PPT];
        #pragma unroll
        for (int i = 0; i < PPT; ++i) {
            La[i] = Aar[cc[i]]; Lb[i] = Bar[cc[i]];
            Sa[i] = Asr[cc[i]]; Sb[i] = Bsr[cc[i]];
        }
        float4 iv[OPT];
        #pragma unroll
        for (int i = 0; i < OPT; ++i)
            iv[i] = Iimg[(size_t)h * ROW4 + T + OPT * t + i];

        int hl = h - r; if (hl < 0) hl = 0;
        int hh = h + r; if (hh > HD - 1) hh = HD - 1;
        const float cntH = (float)(hh - hl + 1);

        scan2d(pl, wt, sA, sB, t, lane, wv);

        float4* Qrow = Qout + imgb + (size_t)h * ROW4 + T + OPT * t;
        #pragma unroll
        for (int i = 0; i < OPT; ++i) {
            int wp = T + OPT * t + i;
            int wl = wp - r; if (wl < 0) wl = 0;
            int wh2 = wp + r; if (wh2 > WD - 1) wh2 = WD - 1;
            float invN = 1.f / ((float)(wh2 - wl + 1) * cntH);
            int iA = idx4(wh2 + 1 - seg0), iB = idx4(wl - seg0);
            float4 mA = f4s(f4sub(pl[0][iA], pl[0][iB]), invN);
            float4 mB = f4s(f4sub(pl[1][iA], pl[1][iB]), invN);
            Qrow[i] = make_float4(mA.x * iv[i].x + mB.x, mA.y * iv[i].y + mB.y,
                                  mA.z * iv[i].z + mB.z, mA.w * iv[i].w + mB.w);
        }

        #pragma unroll
        for (int i = 0; i < PPT; ++i) {
            float4 A1 = f4s(unpack4(La[i]), wa * cw[i]);
            float4 B1 = f4s(unpack4(Lb[i]), wa * cw[i]);
            float4 A2 = f4s(unpack4(Sa[i]), wsb * cw[i]);
            float4 B2 = f4s(unpack4(Sb[i]), wsb * cw[i]);
            sA[i] = f4add(f4sub(sA[i], A2), A1);
            sB[i] = f4add(f4sub(sB[i], B2), B1);
        }
    }
}

extern "C" void kernel_launch(void* const* d_in, const int* in_sizes, int n_in,
                              void* d_out, int out_size, void* d_ws, size_t ws_size,
                              hipStream_t stream)
{
    const float* I = (const float*)d_in[0];
    const float* P = (const float*)d_in[1];
    const int* rptr = (const int*)d_in[2];
    float* out = (float*)d_out;

    const int Bn = (int)(in_sizes[0] / IMGF);              // 4
    const size_t perBatch = 2 * IMG4 * sizeof(H4);         // A,b fp16 = 16 MiB

    int nbChunk = (int)(ws_size / perBatch);
    if (nbChunk < 1) nbChunk = 1;
    if (nbChunk > Bn) nbChunk = Bn;

    for (int b0 = 0; b0 < Bn; b0 += nbChunk) {
        const int nb = (b0 + nbChunk <= Bn) ? nbChunk : (Bn - b0);
        H4* Ah = (H4*)d_ws;
        H4* Bh = Ah + (size_t)nb * IMG4;
        const float4* Ib = (const float4*)(I + (size_t)b0 * IMGF);
        const float4* Pb = (const float4*)(P + (size_t)b0 * IMGF);
        float4* ob = (float4*)(out + (size_t)b0 * IMGF);

        dim3 grid(NTILE * NB, nb);                         // 128 x nb
        kfusedAB<<<grid, TPB, 0, stream>>>(Ib, Pb, Ah, Bh, rptr);
        kfusedQ<<<grid, TPB, 0, stream>>>(Ah, Bh, Ib, ob, rptr);
    }
}